// Round 11
// baseline (229.106 us; speedup 1.0000x reference)
//
#include <hip/hip_runtime.h>

// Problem constants (match reference)
#define N_NODES  4096
#define MAX_PATH 5
#define EDGE_DIM 16

typedef int   iv2 __attribute__((ext_vector_type(2)));
typedef float fv4 __attribute__((ext_vector_type(4)));

#define BLOCK 256

// Binning: 1024 buckets, 4 output rows (= 64 KB f32) per bucket.
#define NBUCKETS   1024
#define ROWS_PB    4                 // N_NODES / NBUCKETS
#define BUCKET_CAP 1344              // avg 977, sigma~31 -> ~12 sigma headroom
#define K3_THREADS 512

// K1: zero bucket counters (first 1024 threads) + precompute
// D[l][e] = dot(edge_attr[e], edge_vector[l]) (2 MB, L2-resident for K2).
__global__ __launch_bounds__(256) void precompute_kernel(
    const float* __restrict__ edge_attr,   // [E, 16]
    const float* __restrict__ edge_vector, // [MAX_PATH, 16]
    float*       __restrict__ D,           // [MAX_PATH, E]
    int*         __restrict__ cnt,         // [NBUCKETS]
    int n_edges)
{
    int t = blockIdx.x * blockDim.x + threadIdx.x;
    if (t < NBUCKETS) cnt[t] = 0;          // re-zeroed EVERY launch (determinism)
    if (t >= n_edges) return;

    const float4* ea = (const float4*)(edge_attr + (size_t)t * EDGE_DIM);
    float4 a0 = ea[0], a1 = ea[1], a2 = ea[2], a3 = ea[3];

#pragma unroll
    for (int l = 0; l < MAX_PATH; ++l) {
        const float4* ev = (const float4*)(edge_vector + l * EDGE_DIM);
        float4 b0 = ev[0], b1 = ev[1], b2 = ev[2], b3 = ev[3];
        float d = a0.x*b0.x + a0.y*b0.y + a0.z*b0.z + a0.w*b0.w
                + a1.x*b1.x + a1.y*b1.y + a1.z*b1.z + a1.w*b1.w
                + a2.x*b2.x + a2.y*b2.y + a2.z*b2.z + a2.w*b2.w
                + a3.x*b3.x + a3.y*b3.y + a3.z*b3.z + a3.w*b3.w;
        D[(size_t)l * n_edges + t] = d;
    }
}

// K2: gather (2 pairs/thread, D gathers are L2 hits) + bucket-append.
// Append targets (counters + 2048 bucket tails) are a few thousand hot
// lines -> all L2-resident; NO cold random DRAM traffic in this kernel.
__global__ __launch_bounds__(256) void gather_bin_kernel(
    const float*         __restrict__ D,        // [MAX_PATH, E]
    const int*           __restrict__ src_idx,  // [P]
    const int*           __restrict__ dst_idx,  // [P]
    const int*           __restrict__ path_idx, // [P, MAX_PATH]
    int*                 __restrict__ cnt,      // [NBUCKETS]
    unsigned short*      __restrict__ keys,     // [NBUCKETS * BUCKET_CAP]
    float*               __restrict__ bvals,    // [NBUCKETS * BUCKET_CAP]
    int n_pairs, int n_edges)
{
    int t  = blockIdx.x * blockDim.x + threadIdx.x;
    int p0 = t * 2;
    if (p0 >= n_pairs) return;

    if (p0 + 1 < n_pairs) {
        const iv2* pp = (const iv2*)(path_idx + (size_t)p0 * MAX_PATH);
        iv2 w0 = pp[0], w1 = pp[1], w2 = pp[2], w3 = pp[3], w4 = pp[4];
        int e[10] = { w0.x, w0.y, w1.x, w1.y, w2.x,
                      w2.y, w3.x, w3.y, w4.x, w4.y };

        float g[10];
#pragma unroll
        for (int j = 0; j < 2; ++j) {
#pragma unroll
            for (int l = 0; l < MAX_PATH; ++l) {
                int idx = e[j * MAX_PATH + l];
                g[j * MAX_PATH + l] = (idx >= 0) ? D[(size_t)l * n_edges + idx] : 0.0f;
            }
        }

        iv2 sv = *(const iv2*)(src_idx + p0);
        iv2 dv = *(const iv2*)(dst_idx + p0);
        int srcs[2] = { sv.x, sv.y };
        int dsts[2] = { dv.x, dv.y };

#pragma unroll
        for (int j = 0; j < 2; ++j) {
            float sum = 0.0f;
            int   c   = 0;
#pragma unroll
            for (int l = 0; l < MAX_PATH; ++l) {
                if (e[j * MAX_PATH + l] >= 0) { sum += g[j * MAX_PATH + l]; ++c; }
            }
            float val = (c > 0) ? (sum / (float)c) : 0.0f;

            int bucket = srcs[j] >> 2;                       // src / ROWS_PB
            int pos    = atomicAdd(&cnt[bucket], 1);
            if (pos < BUCKET_CAP) {
                size_t slot = (size_t)bucket * BUCKET_CAP + pos;
                keys[slot]  = (unsigned short)(((srcs[j] & 3) << 12) | dsts[j]);
                bvals[slot] = val;
            }
        }
    } else {
        for (int p = p0; p < n_pairs; ++p) {
            float sum = 0.0f;
            int   c   = 0;
#pragma unroll
            for (int l = 0; l < MAX_PATH; ++l) {
                int idx = path_idx[(size_t)p * MAX_PATH + l];
                if (idx >= 0) { sum += D[(size_t)l * n_edges + idx]; ++c; }
            }
            float val = (c > 0) ? (sum / (float)c) : 0.0f;
            int s = src_idx[p], d = dst_idx[p];
            int bucket = s >> 2;
            int pos    = atomicAdd(&cnt[bucket], 1);
            if (pos < BUCKET_CAP) {
                size_t slot = (size_t)bucket * BUCKET_CAP + pos;
                keys[slot]  = (unsigned short)(((s & 3) << 12) | d);
                bvals[slot] = val;
            }
        }
    }
}

// K3: one block per bucket. Build the 4-row (64 KB) output stripe in LDS:
// zero it, apply the bucket's records (unique (src,dst) -> no collisions),
// then stream it out fully coalesced. Output is written EXACTLY ONCE ->
// no fill kernel, no random DRAM stores anywhere.
__global__ __launch_bounds__(K3_THREADS) void build_out_kernel(
    const int*            __restrict__ cnt,   // [NBUCKETS]
    const unsigned short* __restrict__ keys,  // [NBUCKETS * BUCKET_CAP]
    const float*          __restrict__ bvals, // [NBUCKETS * BUCKET_CAP]
    float*                __restrict__ out)   // [N_NODES, N_NODES]
{
    extern __shared__ float tile[];            // ROWS_PB * N_NODES = 16384 f32
    const int b   = blockIdx.x;
    const int tid = threadIdx.x;

    fv4* t4 = (fv4*)tile;
    const int nvec = ROWS_PB * N_NODES / 4;    // 4096
    fv4 z = {0.f, 0.f, 0.f, 0.f};
    for (int i = tid; i < nvec; i += K3_THREADS) t4[i] = z;
    __syncthreads();

    int n = cnt[b];
    if (n > BUCKET_CAP) n = BUCKET_CAP;
    const size_t base = (size_t)b * BUCKET_CAP;
    for (int r = tid; r < n; r += K3_THREADS) {
        unsigned short k = keys[base + r];     // (src&3)*4096 + dst, 14 bits
        tile[k] = bvals[base + r];
    }
    __syncthreads();

    fv4* o4 = (fv4*)(out + (size_t)b * ROWS_PB * N_NODES);
    for (int i = tid; i < nvec; i += K3_THREADS)
        o4[i] = t4[i];
}

extern "C" void kernel_launch(void* const* d_in, const int* in_sizes, int n_in,
                              void* d_out, int out_size, void* d_ws, size_t ws_size,
                              hipStream_t stream)
{
    // Input order: x, edge_attr, edge_vector, src_idx, dst_idx, path_idx
    const float* edge_attr   = (const float*)d_in[1];
    const float* edge_vector = (const float*)d_in[2];
    const int*   src_idx     = (const int*)d_in[3];
    const int*   dst_idx     = (const int*)d_in[4];
    const int*   path_idx    = (const int*)d_in[5];
    float*       out         = (float*)d_out;

    const int n_edges = in_sizes[1] / EDGE_DIM;  // 100,000
    const int n_pairs = in_sizes[3];             // 1,000,000

    // Workspace layout (aligned): cnt | D | keys | bvals  (~10.3 MB total)
    char* ws = (char*)d_ws;
    int*            cnt   = (int*)ws;                                   // 4 KB
    float*          D     = (float*)(ws + 4096);                        // 2 MB
    unsigned short* keys  = (unsigned short*)(ws + 4096 +
                              (size_t)MAX_PATH * n_edges * sizeof(float));
    float*          bvals = (float*)((char*)keys +
                              (((size_t)NBUCKETS * BUCKET_CAP * 2 + 255) & ~(size_t)255));

    // K1: counter zero + D precompute
    const int t1 = (n_edges > NBUCKETS ? n_edges : NBUCKETS);
    precompute_kernel<<<(t1 + BLOCK - 1) / BLOCK, BLOCK, 0, stream>>>(
        edge_attr, edge_vector, D, cnt, n_edges);

    // K2: gather + bucket append
    const int t2 = (n_pairs + 1) / 2;
    gather_bin_kernel<<<(t2 + BLOCK - 1) / BLOCK, BLOCK, 0, stream>>>(
        D, src_idx, dst_idx, path_idx, cnt, keys, bvals, n_pairs, n_edges);

    // K3: build output stripes in LDS, stream out (writes ALL of out)
    build_out_kernel<<<NBUCKETS, K3_THREADS,
                       ROWS_PB * N_NODES * sizeof(float), stream>>>(
        cnt, keys, bvals, out);
}

// Round 12
// 55.792 us; speedup vs baseline: 4.1064x; 4.1064x over previous
//
#include <hip/hip_runtime.h>

// Problem constants (match reference)
#define N_NODES  4096
#define MAX_PATH 5
#define EDGE_DIM 16

typedef int   iv2 __attribute__((ext_vector_type(2)));
typedef float fv2 __attribute__((ext_vector_type(2)));
typedef float fv4 __attribute__((ext_vector_type(4)));

#define BLOCK       256
#define FILL_BLOCKS 2048   // 2048*256 threads * 8 fv4 = 4,194,304 = out/4 exactly

// K1: precompute D[l][e] = dot(edge_attr[e], edge_vector[l]) (2 MB, f32).
__global__ __launch_bounds__(256) void precompute_kernel(
    const float* __restrict__ edge_attr,   // [E, 16]
    const float* __restrict__ edge_vector, // [MAX_PATH, 16]
    float*       __restrict__ D,           // [MAX_PATH, E]
    int n_edges)
{
    int e = blockIdx.x * blockDim.x + threadIdx.x;
    if (e >= n_edges) return;

    const float4* ea = (const float4*)(edge_attr + (size_t)e * EDGE_DIM);
    float4 a0 = ea[0], a1 = ea[1], a2 = ea[2], a3 = ea[3];

#pragma unroll
    for (int l = 0; l < MAX_PATH; ++l) {
        const float4* ev = (const float4*)(edge_vector + l * EDGE_DIM);
        float4 b0 = ev[0], b1 = ev[1], b2 = ev[2], b3 = ev[3];
        float d = a0.x*b0.x + a0.y*b0.y + a0.z*b0.z + a0.w*b0.w
                + a1.x*b1.x + a1.y*b1.y + a1.z*b1.z + a1.w*b1.w
                + a2.x*b2.x + a2.y*b2.y + a2.z*b2.z + a2.w*b2.w
                + a3.x*b3.x + a3.y*b3.y + a3.z*b3.z + a3.w*b3.w;
        D[(size_t)l * n_edges + e] = d;
    }
}

// K2: fill ∥ gather via parity-interleaved block roles (both co-resident the
// whole kernel). Even blocks: zero-fill a slice of `out` with normal cached
// fv4 stores (BW-bound). Odd blocks: gather 2 pairs/thread from L2-resident D
// (latency-bound) and write vals[] coalesced. Disjoint outputs -> race-free.
__global__ __launch_bounds__(256) void fill_gather_kernel(
    const float* __restrict__ D,        // [MAX_PATH, E]
    const int*   __restrict__ path_idx, // [P, MAX_PATH]
    float*       __restrict__ vals,     // [P]
    float*       __restrict__ out,      // [N_NODES, N_NODES]
    int n_pairs, int n_edges, int n_gather_blocks)
{
    const int bid     = (int)blockIdx.x;
    const int nPaired = 2 * (FILL_BLOCKS < n_gather_blocks ? FILL_BLOCKS
                                                           : n_gather_blocks);
    bool isFill;
    int  rid;
    if (bid < nPaired) { isFill = ((bid & 1) == 0); rid = bid >> 1; }
    else if (FILL_BLOCKS > n_gather_blocks) { isFill = true;  rid = n_gather_blocks + (bid - nPaired); }
    else                                    { isFill = false; rid = FILL_BLOCKS     + (bid - nPaired); }

    if (isFill) {
        const size_t nvec   = (size_t)N_NODES * N_NODES / 4;
        const size_t stride = (size_t)FILL_BLOCKS * BLOCK;
        fv4 z = {0.f, 0.f, 0.f, 0.f};
        fv4* o4 = (fv4*)out;
        for (size_t i = (size_t)rid * BLOCK + threadIdx.x; i < nvec; i += stride)
            o4[i] = z;
        return;
    }

    int t  = rid * BLOCK + (int)threadIdx.x;
    int p0 = t * 2;
    if (p0 >= n_pairs) return;

    if (p0 + 1 < n_pairs) {
        const iv2* pp = (const iv2*)(path_idx + (size_t)p0 * MAX_PATH);
        iv2 w0 = pp[0], w1 = pp[1], w2 = pp[2], w3 = pp[3], w4 = pp[4];
        int e[10] = { w0.x, w0.y, w1.x, w1.y, w2.x,
                      w2.y, w3.x, w3.y, w4.x, w4.y };

        float g[10];
#pragma unroll
        for (int j = 0; j < 2; ++j) {
#pragma unroll
            for (int l = 0; l < MAX_PATH; ++l) {
                int idx = e[j * MAX_PATH + l];
                g[j * MAX_PATH + l] = (idx >= 0) ? D[(size_t)l * n_edges + idx] : 0.0f;
            }
        }

        fv2 v;
#pragma unroll
        for (int j = 0; j < 2; ++j) {
            float sum = 0.0f;
            int   cnt = 0;
#pragma unroll
            for (int l = 0; l < MAX_PATH; ++l) {
                if (e[j * MAX_PATH + l] >= 0) { sum += g[j * MAX_PATH + l]; ++cnt; }
            }
            v[j] = (cnt > 0) ? (sum / (float)cnt) : 0.0f;
        }
        *(fv2*)(vals + p0) = v;
    } else {
        for (int p = p0; p < n_pairs; ++p) {
            float sum = 0.0f;
            int   cnt = 0;
#pragma unroll
            for (int l = 0; l < MAX_PATH; ++l) {
                int idx = path_idx[(size_t)p * MAX_PATH + l];
                if (idx >= 0) { sum += D[(size_t)l * n_edges + idx]; ++cnt; }
            }
            vals[p] = (cnt > 0) ? (sum / (float)cnt) : 0.0f;
        }
    }
}

// K3: scatter-only. Coalesced float4/int4 reads, 4 random stores/thread.
// Kernel boundary guarantees the fill is complete; out lines L2/L3-warm.
__global__ __launch_bounds__(256) void scatter_vals_kernel(
    const float* __restrict__ vals,     // [P]
    const int*   __restrict__ src_idx,  // [P]
    const int*   __restrict__ dst_idx,  // [P]
    float*       __restrict__ out,      // [N_NODES, N_NODES]
    int n_pairs)
{
    int t  = blockIdx.x * blockDim.x + threadIdx.x;
    int p0 = t * 4;
    if (p0 >= n_pairs) return;

    if (p0 + 3 < n_pairs) {
        float4 v  = *(const float4*)(vals + p0);
        int4   sv = *(const int4*)(src_idx + p0);
        int4   dv = *(const int4*)(dst_idx + p0);
        out[(size_t)sv.x * N_NODES + dv.x] = v.x;
        out[(size_t)sv.y * N_NODES + dv.y] = v.y;
        out[(size_t)sv.z * N_NODES + dv.z] = v.z;
        out[(size_t)sv.w * N_NODES + dv.w] = v.w;
    } else {
        for (int p = p0; p < n_pairs; ++p)
            out[(size_t)src_idx[p] * N_NODES + dst_idx[p]] = vals[p];
    }
}

extern "C" void kernel_launch(void* const* d_in, const int* in_sizes, int n_in,
                              void* d_out, int out_size, void* d_ws, size_t ws_size,
                              hipStream_t stream)
{
    // Input order: x, edge_attr, edge_vector, src_idx, dst_idx, path_idx
    const float* edge_attr   = (const float*)d_in[1];
    const float* edge_vector = (const float*)d_in[2];
    const int*   src_idx     = (const int*)d_in[3];
    const int*   dst_idx     = (const int*)d_in[4];
    const int*   path_idx    = (const int*)d_in[5];
    float*       out         = (float*)d_out;

    const int n_edges = in_sizes[1] / EDGE_DIM;  // 100,000
    const int n_pairs = in_sizes[3];             // 1,000,000

    float* D    = (float*)d_ws;                         // 5*E*4B = 2 MB
    float* vals = (float*)((char*)d_ws +
                  (((size_t)5 * n_edges * sizeof(float) + 1023) & ~(size_t)1023));

    // K1: precompute D (small, ~2 us)
    precompute_kernel<<<(n_edges + BLOCK - 1) / BLOCK, BLOCK, 0, stream>>>(
        edge_attr, edge_vector, D, n_edges);

    // K2: fill (BW-bound) overlapped with gather (latency-bound)
    const int tG = (n_pairs + 1) / 2;
    const int n_gather_blocks = (tG + BLOCK - 1) / BLOCK;   // 1954
    fill_gather_kernel<<<FILL_BLOCKS + n_gather_blocks, BLOCK, 0, stream>>>(
        D, path_idx, vals, out, n_pairs, n_edges, n_gather_blocks);

    // K3: scatter into the warm out buffer
    const int tS = (n_pairs + 3) / 4;
    scatter_vals_kernel<<<(tS + BLOCK - 1) / BLOCK, BLOCK, 0, stream>>>(
        vals, src_idx, dst_idx, out, n_pairs);
}

// Round 13
// 44.608 us; speedup vs baseline: 5.1360x; 1.2507x over previous
//
#include <hip/hip_runtime.h>
#include <hip/hip_fp16.h>

// Problem constants (match reference)
#define N_NODES  4096
#define MAX_PATH 5
#define EDGE_DIM 16

typedef float fv4 __attribute__((ext_vector_type(4)));

#define BLOCK 256
#define FILL_BLOCKS 2048

// K1 (fused): blocks [0, FILL_BLOCKS) zero `out` with NORMAL cached fv4
// stores (leaves lines warm for the scatter; nt regressed twice). Blocks
// [FILL_BLOCKS, ...) precompute D[l][e] = dot(edge_attr[e], edge_vector[l])
// in fp16 (1 MB -> half the L2 footprint during K2's streams).
__global__ __launch_bounds__(256) void fill_and_precompute_kernel(
    const float* __restrict__ edge_attr,   // [E, 16]
    const float* __restrict__ edge_vector, // [MAX_PATH, 16]
    __half*      __restrict__ D,           // [MAX_PATH, E] fp16
    float*       __restrict__ out,         // [N_NODES, N_NODES]
    int n_edges)
{
    if ((int)blockIdx.x < FILL_BLOCKS) {
        const size_t nvec   = (size_t)N_NODES * N_NODES / 4;   // 4.19M fv4
        const size_t stride = (size_t)FILL_BLOCKS * BLOCK;
        fv4 z = {0.f, 0.f, 0.f, 0.f};
        fv4* o4 = (fv4*)out;
        for (size_t i = (size_t)blockIdx.x * BLOCK + threadIdx.x; i < nvec; i += stride)
            o4[i] = z;
        return;
    }

    int e = ((int)blockIdx.x - FILL_BLOCKS) * BLOCK + threadIdx.x;
    if (e >= n_edges) return;

    const float4* ea = (const float4*)(edge_attr + (size_t)e * EDGE_DIM);
    float4 a0 = ea[0], a1 = ea[1], a2 = ea[2], a3 = ea[3];

#pragma unroll
    for (int l = 0; l < MAX_PATH; ++l) {
        const float4* ev = (const float4*)(edge_vector + l * EDGE_DIM);
        float4 b0 = ev[0], b1 = ev[1], b2 = ev[2], b3 = ev[3];
        float d = a0.x*b0.x + a0.y*b0.y + a0.z*b0.z + a0.w*b0.w
                + a1.x*b1.x + a1.y*b1.y + a1.z*b1.z + a1.w*b1.w
                + a2.x*b2.x + a2.y*b2.y + a2.z*b2.z + a2.w*b2.w
                + a3.x*b3.x + a3.y*b3.y + a3.z*b3.z + a3.w*b3.w;
        D[(size_t)l * n_edges + e] = __float2half(d);
    }
}

// K2 (fused): gather + scatter, 4 pairs/thread. int4 path/src/dst loads
// (aligned, no redundant line touches), all 20 D-gathers issued before use
// (deep MLP), then 4 random stores into the L2/L3-warm out buffer.
// Pairs unique -> plain stores, no atomics.
__global__ __launch_bounds__(256) void gather_scatter_kernel(
    const __half* __restrict__ D,        // [MAX_PATH, E]
    const int*    __restrict__ src_idx,  // [P]
    const int*    __restrict__ dst_idx,  // [P]
    const int*    __restrict__ path_idx, // [P, MAX_PATH]
    float*        __restrict__ out,      // [N_NODES, N_NODES]
    int n_pairs, int n_edges)
{
    int t  = blockIdx.x * blockDim.x + threadIdx.x;
    int p0 = t * 4;
    if (p0 >= n_pairs) return;

    if (p0 + 3 < n_pairs) {
        // 20 path ints for 4 pairs = 5 aligned int4 loads.
        const int4* pp = (const int4*)(path_idx + (size_t)p0 * MAX_PATH);
        int4 w0 = pp[0], w1 = pp[1], w2 = pp[2], w3 = pp[3], w4 = pp[4];
        int e[20] = { w0.x, w0.y, w0.z, w0.w,
                      w1.x, w1.y, w1.z, w1.w,
                      w2.x, w2.y, w2.z, w2.w,
                      w3.x, w3.y, w3.z, w3.w,
                      w4.x, w4.y, w4.z, w4.w };

        // Issue all gathers before any use (independent -> deep MLP).
        float g[20];
#pragma unroll
        for (int j = 0; j < 4; ++j) {
#pragma unroll
            for (int l = 0; l < MAX_PATH; ++l) {
                int idx = e[j * MAX_PATH + l];
                g[j * MAX_PATH + l] =
                    (idx >= 0) ? __half2float(D[(size_t)l * n_edges + idx]) : 0.0f;
            }
        }

        int4 sv = *(const int4*)(src_idx + p0);
        int4 dv = *(const int4*)(dst_idx + p0);
        int srcs[4] = { sv.x, sv.y, sv.z, sv.w };
        int dsts[4] = { dv.x, dv.y, dv.z, dv.w };

#pragma unroll
        for (int j = 0; j < 4; ++j) {
            float sum = 0.0f;
            int   cnt = 0;
#pragma unroll
            for (int l = 0; l < MAX_PATH; ++l) {
                if (e[j * MAX_PATH + l] >= 0) { sum += g[j * MAX_PATH + l]; ++cnt; }
            }
            float val = (cnt > 0) ? (sum / (float)cnt) : 0.0f;
            out[(size_t)srcs[j] * N_NODES + dsts[j]] = val;
        }
    } else {
        for (int p = p0; p < n_pairs; ++p) {
            float sum = 0.0f;
            int   cnt = 0;
#pragma unroll
            for (int l = 0; l < MAX_PATH; ++l) {
                int idx = path_idx[(size_t)p * MAX_PATH + l];
                if (idx >= 0) { sum += __half2float(D[(size_t)l * n_edges + idx]); ++cnt; }
            }
            float val = (cnt > 0) ? (sum / (float)cnt) : 0.0f;
            out[(size_t)src_idx[p] * N_NODES + dst_idx[p]] = val;
        }
    }
}

extern "C" void kernel_launch(void* const* d_in, const int* in_sizes, int n_in,
                              void* d_out, int out_size, void* d_ws, size_t ws_size,
                              hipStream_t stream)
{
    // Input order: x, edge_attr, edge_vector, src_idx, dst_idx, path_idx
    const float* edge_attr   = (const float*)d_in[1];
    const float* edge_vector = (const float*)d_in[2];
    const int*   src_idx     = (const int*)d_in[3];
    const int*   dst_idx     = (const int*)d_in[4];
    const int*   path_idx    = (const int*)d_in[5];
    float*       out         = (float*)d_out;
    __half*      D           = (__half*)d_ws;   // 5*E*2B = 1 MB

    const int n_edges = in_sizes[1] / EDGE_DIM;  // 100,000
    const int n_pairs = in_sizes[3];             // 1,000,000

    // K1: fill (2048 blocks) + precompute D (~391 blocks), disjoint outputs.
    const int pre_blocks = (n_edges + BLOCK - 1) / BLOCK;
    fill_and_precompute_kernel<<<FILL_BLOCKS + pre_blocks, BLOCK, 0, stream>>>(
        edge_attr, edge_vector, D, out, n_edges);

    // K2: fused gather + scatter.
    const int t2 = (n_pairs + 3) / 4;
    gather_scatter_kernel<<<(t2 + BLOCK - 1) / BLOCK, BLOCK, 0, stream>>>(
        D, src_idx, dst_idx, path_idx, out, n_pairs, n_edges);
}